// Round 1
// baseline (325.170 us; speedup 1.0000x reference)
//
#include <hip/hip_runtime.h>

typedef unsigned int u32;
typedef unsigned short u16;

typedef __attribute__((ext_vector_type(8))) short short8v;   // 8 x bf16 bits (4 VGPRs)
typedef __attribute__((ext_vector_type(4))) float f32x4;

#define AS_GLOBAL __attribute__((address_space(1)))
#define AS_LDS    __attribute__((address_space(3)))

static __device__ __forceinline__ u16 f32_bf16_rne(float f) {
  u32 u = __builtin_bit_cast(u32, f);
  u32 lsb = (u >> 16) & 1u;
  u += 0x7fffu + lsb;
  return (u16)(u >> 16);
}

// ---------------------------------------------------------------------------
// Pass 1: quotient-remainder fake quant, f32 -> bf16 bits.
// One group (GS=128) per 16-lane subgroup; 8 elems/lane.
// NOTE: base >= 2 always, so the reference's sel_mask (base < 1.0) is
// provably always false -> selective-int branch omitted.
// ---------------------------------------------------------------------------
__global__ __launch_bounds__(256) void quant_kernel(
    const float* __restrict__ x, u16* __restrict__ xq) {
  const int tid = blockIdx.x * 256 + threadIdx.x;
  const int grp = tid >> 4;
  const int l   = tid & 15;
  const size_t base_e = (size_t)grp * 128;
  const float* gx = x + base_e;

  float4 v0 = *(const float4*)(gx + l * 4);
  float4 v1 = *(const float4*)(gx + 64 + l * 4);
  float xs[8] = {v0.x, v0.y, v0.z, v0.w, v1.x, v1.y, v1.z, v1.w};

  float mabs = 0.f;
  #pragma unroll
  for (int i = 0; i < 8; ++i) mabs = fmaxf(mabs, fabsf(xs[i]));
  #pragma unroll
  for (int s = 1; s < 16; s <<= 1) mabs = fmaxf(mabs, __shfl_xor(mabs, s, 16));
  mabs = fmaxf(mabs, 1e-8f);

  const float thr = mabs / 7.0f;            // true division: matches np
  float base = 64.f;
  base = (thr <= 32.f) ? 32.f : base;
  base = (thr <= 16.f) ? 16.f : base;
  base = (thr <= 8.f)  ? 8.f  : base;
  base = (thr <= 4.f)  ? 4.f  : base;
  base = (thr <= 2.f)  ? 2.f  : base;
  const float rbase = 1.0f / base;          // exact (power of 2)

  float q[8], r[8];
  float mr = 0.f;
  #pragma unroll
  for (int i = 0; i < 8; ++i) {
    float qq = rintf(xs[i] * rbase);        // == rintf(xs/base), exact scale
    qq = fminf(fmaxf(qq, -7.f), 7.f);
    q[i] = qq;
    r[i] = xs[i] - base * qq;               // exact product, IEEE sub
    mr = fmaxf(mr, fabsf(r[i]));
  }
  #pragma unroll
  for (int s = 1; s < 16; s <<= 1) mr = fmaxf(mr, __shfl_xor(mr, s, 16));
  float rs = fmaxf(mr, 1e-8f) / 7.0f;
  rs = fmaxf(rs, 1e-8f);

  u16 o[8];
  #pragma unroll
  for (int i = 0; i < 8; ++i) {
    float rd = rintf(r[i] / rs);            // IEEE division: matches np
    rd = fminf(fmaxf(rd, -8.f), 7.f) * rs;
    o[i] = f32_bf16_rne(q[i] * base + rd);
  }
  uint2 p0, p1;
  p0.x = (u32)o[0] | ((u32)o[1] << 16);
  p0.y = (u32)o[2] | ((u32)o[3] << 16);
  p1.x = (u32)o[4] | ((u32)o[5] << 16);
  p1.y = (u32)o[6] | ((u32)o[7] << 16);
  *(uint2*)(xq + base_e + l * 4) = p0;
  *(uint2*)(xq + base_e + 64 + l * 4) = p1;
}

// ---------------------------------------------------------------------------
// Pass 2: weight f32 -> bf16 bits (weight is already 4-bit fake-quantized).
// ---------------------------------------------------------------------------
__global__ __launch_bounds__(256) void wconv_kernel(
    const float* __restrict__ w, u16* __restrict__ wq) {
  const int i = (blockIdx.x * 256 + threadIdx.x) * 4;
  float4 v = *(const float4*)(w + i);
  uint2 p;
  p.x = (u32)f32_bf16_rne(v.x) | ((u32)f32_bf16_rne(v.y) << 16);
  p.y = (u32)f32_bf16_rne(v.z) | ((u32)f32_bf16_rne(v.w) << 16);
  *(uint2*)(wq + i) = p;
}

// ---------------------------------------------------------------------------
// Pass 3: bf16 MFMA GEMM. out[m][n] = sum_k A[m][k]*B[n][k] + bias[n]
// 128x128 tile, BK=64, 4 waves (2x2), 16x16x32 MFMA, 4x4 frags/wave.
// global_load_lds dwordx4 staging with pre-swizzled global source;
// ds_read_b128 with XOR swizzle (byte ^= (row&7)<<4) -> ~conflict-free.
// ---------------------------------------------------------------------------
#define BM 128
#define BN 128
#define BK 64

__global__ __launch_bounds__(256) void gemm_kernel(
    const u16* __restrict__ A, const u16* __restrict__ B,
    const float* __restrict__ bias, float* __restrict__ out,
    int M, int N, int K) {
  __shared__ u16 Asm[BM * BK];   // 16 KiB, linear [row][64], swizzled content
  __shared__ u16 Bsm[BN * BK];   // 16 KiB

  const int tid  = threadIdx.x;
  const int w    = tid >> 6;
  const int lane = tid & 63;
  const int l16  = lane & 15;
  const int quad = lane >> 4;

  const int ntiles = N / BN;
  const int nt = blockIdx.x % ntiles;
  const int mt = blockIdx.x / ntiles;
  const int m0 = mt * BM, n0 = nt * BN;
  const int wm = (w >> 1) * 64, wn = (w & 1) * 64;

  // staging geometry: chunk = 1 KiB = 8 rows of 128B; lane -> (row, slot)
  const int srow  = lane >> 3;              // row within chunk, == row&7
  const int sslot = (lane & 7) ^ srow;      // pre-swizzled source 16B slot

  f32x4 acc[4][4];
  #pragma unroll
  for (int i = 0; i < 4; ++i)
    #pragma unroll
    for (int j = 0; j < 4; ++j)
      acc[i][j] = (f32x4){0.f, 0.f, 0.f, 0.f};

  for (int k0 = 0; k0 < K; k0 += BK) {
    #pragma unroll
    for (int i = 0; i < 4; ++i) {
      const int chunk = w * 4 + i;
      const int row = chunk * 8 + srow;
      const u16* ga = A + (size_t)(m0 + row) * K + (k0 + sslot * 8);
      __builtin_amdgcn_global_load_lds((AS_GLOBAL u32*)(void*)ga,
                                       (AS_LDS u32*)(Asm + chunk * 512), 16, 0, 0);
      const u16* gb = B + (size_t)(n0 + row) * K + (k0 + sslot * 8);
      __builtin_amdgcn_global_load_lds((AS_GLOBAL u32*)(void*)gb,
                                       (AS_LDS u32*)(Bsm + chunk * 512), 16, 0, 0);
    }
    __syncthreads();   // drains vmcnt before barrier -> tiles visible

    #pragma unroll
    for (int kk = 0; kk < BK; kk += 32) {
      const int kbl = kk * 2 + quad * 16;          // linear byte col
      const int sw  = kbl ^ ((l16 & 7) << 4);      // read-side XOR swizzle
      short8v a[4], b[4];
      #pragma unroll
      for (int f = 0; f < 4; ++f) {
        const int arow = wm + f * 16 + l16;        // arow&7 == l16&7
        a[f] = *(const short8v*)((const char*)Asm + arow * 128 + sw);
        const int brow = wn + f * 16 + l16;
        b[f] = *(const short8v*)((const char*)Bsm + brow * 128 + sw);
      }
      #pragma unroll
      for (int fm = 0; fm < 4; ++fm)
        #pragma unroll
        for (int fn = 0; fn < 4; ++fn)
          acc[fm][fn] = __builtin_amdgcn_mfma_f32_16x16x32_bf16(
              a[fm], b[fn], acc[fm][fn], 0, 0, 0);
    }
    __syncthreads();
  }

  // epilogue: C/D layout col = lane&15, row = quad*4 + j  [m89/m91]
  #pragma unroll
  for (int fn = 0; fn < 4; ++fn) {
    const int col = n0 + wn + fn * 16 + l16;
    const float bv = bias[col];
    #pragma unroll
    for (int fm = 0; fm < 4; ++fm) {
      const int rbase2 = m0 + wm + fm * 16 + quad * 4;
      #pragma unroll
      for (int j = 0; j < 4; ++j)
        out[(size_t)(rbase2 + j) * N + col] = acc[fm][fn][j] + bv;
    }
  }
}

// ---------------------------------------------------------------------------
extern "C" void kernel_launch(void* const* d_in, const int* in_sizes, int n_in,
                              void* d_out, int out_size, void* d_ws, size_t ws_size,
                              hipStream_t stream) {
  const float* x    = (const float*)d_in[0];   // [8,8192,1024] f32
  const float* wgt  = (const float*)d_in[1];   // [1024,1024] f32
  const float* bias = (const float*)d_in[2];   // [1024] f32
  float* out = (float*)d_out;                  // [8,8192,1024] f32

  const int K = 1024, N = 1024;
  const int M = in_sizes[0] / K;               // 65536

  // workspace: xq bf16 (M*K*2 = 128 MiB) then wq bf16 (N*K*2 = 2 MiB)
  u16* xq = (u16*)d_ws;
  u16* wq = xq + (size_t)M * K;

  const int ngroups = (M * K) / 128;           // 524288
  quant_kernel<<<ngroups / 16, 256, 0, stream>>>(x, xq);
  wconv_kernel<<<(N * K) / 1024, 256, 0, stream>>>(wgt, wq);
  gemm_kernel<<<(M / BM) * (N / BN), 256, 0, stream>>>(xq, wq, bias, out, M, N, K);
}

// Round 2
// 281.123 us; speedup vs baseline: 1.1567x; 1.1567x over previous
//
#include <hip/hip_runtime.h>

typedef unsigned int u32;
typedef unsigned short u16;

typedef __attribute__((ext_vector_type(8))) short short8v;   // 8 x bf16 bits (4 VGPRs)
typedef __attribute__((ext_vector_type(4))) float f32x4;

#define AS_GLOBAL __attribute__((address_space(1)))
#define AS_LDS    __attribute__((address_space(3)))

static __device__ __forceinline__ u16 f32_bf16_rne(float f) {
  u32 u = __builtin_bit_cast(u32, f);
  u32 lsb = (u >> 16) & 1u;
  u += 0x7fffu + lsb;
  return (u16)(u >> 16);
}

// ---------------------------------------------------------------------------
// Pass 1: quotient-remainder fake quant, f32 -> bf16 bits.
// One group (GS=128) per 16-lane subgroup; 8 elems/lane.
// base >= 2 always, so reference's sel_mask (base < 1.0) is always false.
// ---------------------------------------------------------------------------
__global__ __launch_bounds__(256) void quant_kernel(
    const float* __restrict__ x, u16* __restrict__ xq) {
  const int tid = blockIdx.x * 256 + threadIdx.x;
  const int grp = tid >> 4;
  const int l   = tid & 15;
  const size_t base_e = (size_t)grp * 128;
  const float* gx = x + base_e;

  float4 v0 = *(const float4*)(gx + l * 4);
  float4 v1 = *(const float4*)(gx + 64 + l * 4);
  float xs[8] = {v0.x, v0.y, v0.z, v0.w, v1.x, v1.y, v1.z, v1.w};

  float mabs = 0.f;
  #pragma unroll
  for (int i = 0; i < 8; ++i) mabs = fmaxf(mabs, fabsf(xs[i]));
  #pragma unroll
  for (int s = 1; s < 16; s <<= 1) mabs = fmaxf(mabs, __shfl_xor(mabs, s, 16));
  mabs = fmaxf(mabs, 1e-8f);

  const float thr = mabs / 7.0f;            // true division: matches np
  float base = 64.f;
  base = (thr <= 32.f) ? 32.f : base;
  base = (thr <= 16.f) ? 16.f : base;
  base = (thr <= 8.f)  ? 8.f  : base;
  base = (thr <= 4.f)  ? 4.f  : base;
  base = (thr <= 2.f)  ? 2.f  : base;
  const float rbase = 1.0f / base;          // exact (power of 2)

  float q[8], r[8];
  float mr = 0.f;
  #pragma unroll
  for (int i = 0; i < 8; ++i) {
    float qq = rintf(xs[i] * rbase);        // == rintf(xs/base), exact scale
    qq = fminf(fmaxf(qq, -7.f), 7.f);
    q[i] = qq;
    r[i] = xs[i] - base * qq;               // exact product, IEEE sub
    mr = fmaxf(mr, fabsf(r[i]));
  }
  #pragma unroll
  for (int s = 1; s < 16; s <<= 1) mr = fmaxf(mr, __shfl_xor(mr, s, 16));
  float rs = fmaxf(mr, 1e-8f) / 7.0f;
  rs = fmaxf(rs, 1e-8f);

  u16 o[8];
  #pragma unroll
  for (int i = 0; i < 8; ++i) {
    float rd = rintf(r[i] / rs);            // IEEE division: matches np
    rd = fminf(fmaxf(rd, -8.f), 7.f) * rs;
    o[i] = f32_bf16_rne(q[i] * base + rd);
  }
  uint2 p0, p1;
  p0.x = (u32)o[0] | ((u32)o[1] << 16);
  p0.y = (u32)o[2] | ((u32)o[3] << 16);
  p1.x = (u32)o[4] | ((u32)o[5] << 16);
  p1.y = (u32)o[6] | ((u32)o[7] << 16);
  *(uint2*)(xq + base_e + l * 4) = p0;
  *(uint2*)(xq + base_e + 64 + l * 4) = p1;
}

// ---------------------------------------------------------------------------
// Pass 2: weight f32 -> bf16 bits.
// ---------------------------------------------------------------------------
__global__ __launch_bounds__(256) void wconv_kernel(
    const float* __restrict__ w, u16* __restrict__ wq) {
  const int i = (blockIdx.x * 256 + threadIdx.x) * 4;
  float4 v = *(const float4*)(w + i);
  uint2 p;
  p.x = (u32)f32_bf16_rne(v.x) | ((u32)f32_bf16_rne(v.y) << 16);
  p.y = (u32)f32_bf16_rne(v.z) | ((u32)f32_bf16_rne(v.w) << 16);
  *(uint2*)(wq + i) = p;
}

// ---------------------------------------------------------------------------
// Pass 3: bf16 MFMA GEMM, 256x256 tile, BK=64, 8 waves (2Mx4N), counted-vmcnt
// double-buffered pipeline (T1+T2+T3/T4+T5).
//   - STAGE(t+1) issued BEFORE waiting on STAGE(t): vmcnt(8) drains exactly
//     the older 8 loads (FIFO), raw s_barrier makes it collective.
//   - LDS XOR swizzle (byte ^= (row&7)<<4) via pre-swizzled global source.
//   - XCD-chunked blockIdx swizzle: 4 consecutive logical tiles (same mt)
//     per XCD -> A panel L2-resident; whole B (2 MB) fits each L2.
// ---------------------------------------------------------------------------
#define BM 256
#define BN 256
#define BK 64
#define TBUF 16384   // u16 elems per K-tile buffer (256 rows x 64 cols)

__global__ __launch_bounds__(512, 2) void gemm_kernel(
    const u16* __restrict__ A, const u16* __restrict__ B,
    const float* __restrict__ bias, float* __restrict__ out,
    int M, int N, int K) {
  __shared__ u16 lds[4 * TBUF];   // 128 KiB: A0 A1 B0 B1

  const int tid  = threadIdx.x;
  const int w    = tid >> 6;
  const int lane = tid & 63;
  const int l16  = lane & 15;
  const int quad = lane >> 4;

  // staging geometry: chunk = 8 rows x 128B = 1 KiB; lane -> (row, swz slot)
  const int srow  = lane >> 3;
  const int sslot = (lane & 7) ^ srow;

  // XCD chunked swizzle (nwg = 1024, divisible by 8)
  const int nwg = gridDim.x;
  const int cpx = nwg >> 3;
  const int logical = (blockIdx.x & 7) * cpx + (blockIdx.x >> 3);
  const int ntiles = N / BN;
  const int nt = logical % ntiles;
  const int mt = logical / ntiles;
  const int m0 = mt * BM, n0 = nt * BN;
  const int wm = (w >> 2) * 128, wn = (w & 3) * 64;

  u16* As0 = lds;
  u16* As1 = lds + TBUF;
  u16* Bs0 = lds + 2 * TBUF;
  u16* Bs1 = lds + 3 * TBUF;

  auto stage = [&](const u16* __restrict__ G, u16* dst, int row0, int k0) {
    #pragma unroll
    for (int i = 0; i < 4; ++i) {
      const int chunk = w * 4 + i;               // 32 chunks cover 256 rows
      const int row = chunk * 8 + srow;
      const u16* g = G + (size_t)(row0 + row) * K + (k0 + sslot * 8);
      __builtin_amdgcn_global_load_lds((const AS_GLOBAL u32*)(const void*)g,
                                       (AS_LDS u32*)(dst + chunk * 512), 16, 0, 0);
    }
  };

  f32x4 acc[8][4];
  #pragma unroll
  for (int f = 0; f < 8; ++f)
    #pragma unroll
    for (int g = 0; g < 4; ++g)
      acc[f][g] = (f32x4){0.f, 0.f, 0.f, 0.f};

  // prologue: stage K-tile 0 (8 loads/thread outstanding)
  stage(A, As0, m0, 0);
  stage(B, Bs0, n0, 0);

  const int NT = K / BK;   // 16
  for (int t = 0; t < NT; ++t) {
    u16* curA = (t & 1) ? As1 : As0;
    u16* curB = (t & 1) ? Bs1 : Bs0;
    if (t + 1 < NT) {
      // issue next tile's 8 loads FIRST, then wait only for current tile's 8
      stage(A, (t & 1) ? As0 : As1, m0, (t + 1) * BK);
      stage(B, (t & 1) ? Bs0 : Bs1, n0, (t + 1) * BK);
      asm volatile("s_waitcnt vmcnt(8)" ::: "memory");
    } else {
      asm volatile("s_waitcnt vmcnt(0)" ::: "memory");
    }
    asm volatile("s_barrier" ::: "memory");       // cur tile visible, no drain

    #pragma unroll
    for (int kk = 0; kk < 2; ++kk) {              // two K=32 substeps
      const int sw = (kk * 64 + quad * 16) ^ ((l16 & 7) << 4);
      short8v a[8], b[4];
      #pragma unroll
      for (int f = 0; f < 8; ++f)
        a[f] = *(const short8v*)((const char*)curA + (wm + f * 16 + l16) * 128 + sw);
      #pragma unroll
      for (int g = 0; g < 4; ++g)
        b[g] = *(const short8v*)((const char*)curB + (wn + g * 16 + l16) * 128 + sw);
      __builtin_amdgcn_s_setprio(1);
      #pragma unroll
      for (int f = 0; f < 8; ++f)
        #pragma unroll
        for (int g = 0; g < 4; ++g)
          acc[f][g] = __builtin_amdgcn_mfma_f32_16x16x32_bf16(
              a[f], b[g], acc[f][g], 0, 0, 0);
      __builtin_amdgcn_s_setprio(0);
    }
    asm volatile("s_barrier" ::: "memory");       // reads done before overwrite
  }

  // epilogue: C/D layout col = lane&15, row = quad*4 + j
  #pragma unroll
  for (int g = 0; g < 4; ++g) {
    const int col = n0 + wn + g * 16 + l16;
    const float bv = bias[col];
    #pragma unroll
    for (int f = 0; f < 8; ++f) {
      const int r0 = m0 + wm + f * 16 + quad * 4;
      #pragma unroll
      for (int j = 0; j < 4; ++j)
        out[(size_t)(r0 + j) * N + col] = acc[f][g][j] + bv;
    }
  }
}

// ---------------------------------------------------------------------------
extern "C" void kernel_launch(void* const* d_in, const int* in_sizes, int n_in,
                              void* d_out, int out_size, void* d_ws, size_t ws_size,
                              hipStream_t stream) {
  const float* x    = (const float*)d_in[0];   // [8,8192,1024] f32
  const float* wgt  = (const float*)d_in[1];   // [1024,1024] f32
  const float* bias = (const float*)d_in[2];   // [1024] f32
  float* out = (float*)d_out;                  // [8,8192,1024] f32

  const int K = 1024, N = 1024;
  const int M = in_sizes[0] / K;               // 65536

  u16* xq = (u16*)d_ws;                        // 128 MiB bf16
  u16* wq = xq + (size_t)M * K;                // 2 MiB bf16

  const int ngroups = (M * K) / 128;
  quant_kernel<<<ngroups / 16, 256, 0, stream>>>(x, xq);
  wconv_kernel<<<(N * K) / 1024, 256, 0, stream>>>(wgt, wq);
  gemm_kernel<<<(M / BM) * (N / BN), 512, 0, stream>>>(xq, wq, bias, out, M, N, K);
}

// Round 3
// 272.302 us; speedup vs baseline: 1.1942x; 1.0324x over previous
//
#include <hip/hip_runtime.h>

typedef unsigned int u32;
typedef unsigned short u16;

typedef __attribute__((ext_vector_type(8))) short short8v;   // 8 x bf16 bits
typedef __attribute__((ext_vector_type(4))) float f32x4;

#define AS_GLOBAL __attribute__((address_space(1)))
#define AS_LDS    __attribute__((address_space(3)))

static __device__ __forceinline__ u16 f32_bf16_rne(float f) {
  u32 u = __builtin_bit_cast(u32, f);
  u32 lsb = (u >> 16) & 1u;
  u += 0x7fffu + lsb;
  return (u16)(u >> 16);
}

// ---------------------------------------------------------------------------
// Pass 1: quotient-remainder fake quant, f32 -> bf16 bits.
// One group (GS=128) per 16-lane subgroup; 8 elems/lane.
// base >= 2 always, so reference's sel_mask (base < 1.0) is always false.
// ---------------------------------------------------------------------------
__global__ __launch_bounds__(256) void quant_kernel(
    const float* __restrict__ x, u16* __restrict__ xq) {
  const int tid = blockIdx.x * 256 + threadIdx.x;
  const int grp = tid >> 4;
  const int l   = tid & 15;
  const size_t base_e = (size_t)grp * 128;
  const float* gx = x + base_e;

  float4 v0 = *(const float4*)(gx + l * 4);
  float4 v1 = *(const float4*)(gx + 64 + l * 4);
  float xs[8] = {v0.x, v0.y, v0.z, v0.w, v1.x, v1.y, v1.z, v1.w};

  float mabs = 0.f;
  #pragma unroll
  for (int i = 0; i < 8; ++i) mabs = fmaxf(mabs, fabsf(xs[i]));
  #pragma unroll
  for (int s = 1; s < 16; s <<= 1) mabs = fmaxf(mabs, __shfl_xor(mabs, s, 16));
  mabs = fmaxf(mabs, 1e-8f);

  const float thr = mabs / 7.0f;            // true division: matches np
  float base = 64.f;
  base = (thr <= 32.f) ? 32.f : base;
  base = (thr <= 16.f) ? 16.f : base;
  base = (thr <= 8.f)  ? 8.f  : base;
  base = (thr <= 4.f)  ? 4.f  : base;
  base = (thr <= 2.f)  ? 2.f  : base;
  const float rbase = 1.0f / base;          // exact (power of 2)

  float q[8], r[8];
  float mr = 0.f;
  #pragma unroll
  for (int i = 0; i < 8; ++i) {
    float qq = rintf(xs[i] * rbase);        // == rintf(xs/base), exact scale
    qq = fminf(fmaxf(qq, -7.f), 7.f);
    q[i] = qq;
    r[i] = xs[i] - base * qq;               // exact product, IEEE sub
    mr = fmaxf(mr, fabsf(r[i]));
  }
  #pragma unroll
  for (int s = 1; s < 16; s <<= 1) mr = fmaxf(mr, __shfl_xor(mr, s, 16));
  float rs = fmaxf(mr, 1e-8f) / 7.0f;
  rs = fmaxf(rs, 1e-8f);

  u16 o[8];
  #pragma unroll
  for (int i = 0; i < 8; ++i) {
    float rd = rintf(r[i] / rs);            // IEEE division: matches np
    rd = fminf(fmaxf(rd, -8.f), 7.f) * rs;
    o[i] = f32_bf16_rne(q[i] * base + rd);
  }
  uint2 p0, p1;
  p0.x = (u32)o[0] | ((u32)o[1] << 16);
  p0.y = (u32)o[2] | ((u32)o[3] << 16);
  p1.x = (u32)o[4] | ((u32)o[5] << 16);
  p1.y = (u32)o[6] | ((u32)o[7] << 16);
  *(uint2*)(xq + base_e + l * 4) = p0;
  *(uint2*)(xq + base_e + 64 + l * 4) = p1;
}

// ---------------------------------------------------------------------------
// Pass 2: weight f32 -> bf16 bits.
// ---------------------------------------------------------------------------
__global__ __launch_bounds__(256) void wconv_kernel(
    const float* __restrict__ w, u16* __restrict__ wq) {
  const int i = (blockIdx.x * 256 + threadIdx.x) * 4;
  float4 v = *(const float4*)(w + i);
  uint2 p;
  p.x = (u32)f32_bf16_rne(v.x) | ((u32)f32_bf16_rne(v.y) << 16);
  p.y = (u32)f32_bf16_rne(v.z) | ((u32)f32_bf16_rne(v.w) << 16);
  *(uint2*)(wq + i) = p;
}

// ---------------------------------------------------------------------------
// Pass 3: bf16 MFMA GEMM, 256x256 tile, BK=64, 8 waves (2Mx4N), 8-phase
// schedule (4 phases per K-tile), K-half-granular staging, counted vmcnt(6).
//
// LDS byte map (128 KiB): A[p] at p*32768, B[p] at 65536 + p*32768.
// Within a buffer: ksub*16384 + row*64 + slot'*16, slot' = kslot ^ ((row>>1)&3)
// (kslot = k-16B-slot within the 32-col K-half). DMA dest linear; source
// pre-swizzled per-lane; ds_read applies the same XOR -> bank-balanced b128.
//
// Stage stream (3 half-tiles ahead, vmcnt(6) at ph3 only):
//   ph0: B[p^1] k1 (tile t+1)   ph1: A[p] k0 (t+2)
//   ph2: B[p]  k0 (t+2)         ph3: A[p] k1 (t+2)
// Each target's last reader finished at least one barrier earlier.
// ds_reads are issued one phase ahead (alternating reg banks aA/aB, b0/b1);
// ph3's next-tile reads issue AFTER vmcnt(6)+barrier (cross-wave visibility).
// ---------------------------------------------------------------------------
#define BM 256
#define BN 256
#define BK 64

__global__ __launch_bounds__(512, 2) void gemm_kernel(
    const u16* __restrict__ A, const u16* __restrict__ B,
    const float* __restrict__ bias, float* __restrict__ out,
    int M, int N, int K) {
  __shared__ u16 lds[65536];   // 128 KiB

  const int tid  = threadIdx.x;
  const int w    = tid >> 6;
  const int lane = tid & 63;
  const int l16  = lane & 15;
  const int quad = lane >> 4;

  // XCD chunked swizzle (nwg divisible by 8)
  const int nwg = gridDim.x;
  const int cpx = nwg >> 3;
  const int logical = (blockIdx.x & 7) * cpx + (blockIdx.x >> 3);
  const int ntiles = N / BN;
  const int nt = logical % ntiles;
  const int mt = logical / ntiles;
  const int m0 = mt * BM, n0 = nt * BN;
  const int wm = (w >> 2) * 128, wn = (w & 3) * 64;

  const int swz  = (quad ^ ((l16 >> 1) & 3)) << 4;
  const int aoff = (wm + l16) * 64 + swz;
  const int boff = (wn + l16) * 64 + swz;

  // stage one K-half (16 KB): 2 x global_load_lds dwordx4 per thread
  auto stage_half = [&](const u16* __restrict__ G, int base_b, int r0, int k0) {
    #pragma unroll
    for (int i = 0; i < 2; ++i) {
      const int c = w * 2 + i;                       // 0..15 chunks of 1 KiB
      const int row = c * 16 + (lane >> 2);
      const int kslot = (lane & 3) ^ ((lane >> 3) & 3);   // pre-swizzled src
      const u16* g = G + (size_t)(r0 + row) * K + (k0 + kslot * 8);
      __builtin_amdgcn_global_load_lds((const AS_GLOBAL u32*)(const void*)g,
          (AS_LDS u32*)(void*)((char*)lds + base_b + c * 1024), 16, 0, 0);
    }
  };

  auto LDA = [&](int base_b, int s, int f) {
    return *(const short8v*)((const char*)lds + base_b + s * 16384 + f * 1024 + aoff);
  };
  auto LDB = [&](int base_b, int s, int g) {
    return *(const short8v*)((const char*)lds + base_b + s * 16384 + g * 1024 + boff);
  };

  f32x4 acc[8][4];
  #pragma unroll
  for (int f = 0; f < 8; ++f)
    #pragma unroll
    for (int g = 0; g < 4; ++g)
      acc[f][g] = (f32x4){0.f, 0.f, 0.f, 0.f};

  short8v aA[8], aB[8], b0[2], b1[2];

  const int NT = K / BK;   // 16

  // prologue: stage tile0 (4 halves) + tile1 (3 halves), stream order
  stage_half(A, 0,             m0, 0);    // A0 k0
  stage_half(B, 65536,         n0, 0);    // B0 k0
  stage_half(A, 16384,         m0, 32);   // A0 k1
  stage_half(B, 65536 + 16384, n0, 32);   // B0 k1
  stage_half(A, 32768,         m0, 64);   // A1 k0
  stage_half(B, 65536 + 32768, n0, 64);   // B1 k0
  stage_half(A, 32768 + 16384, m0, 96);   // A1 k1
  asm volatile("s_waitcnt vmcnt(6)" ::: "memory");   // tile0's 8 loads done
  asm volatile("s_barrier" ::: "memory");

  // pre-issue reads for t=0 phase 0 (parity 0)
  #pragma unroll
  for (int f = 0; f < 8; ++f) aA[f] = LDA(0, 0, f);
  b0[0] = LDB(65536, 0, 0);
  b0[1] = LDB(65536, 0, 1);

  for (int t = 0; t < NT; ++t) {
    const int p   = t & 1;
    const int pAb = p * 32768;
    const int pBb = 65536 + p * 32768;
    const int qAb = (p ^ 1) * 32768;
    const int qBb = 65536 + (p ^ 1) * 32768;
    const int k2  = (t + 2) * 64;

    // -------- phase 0: MFMA (k0, fn 0-1); read b(k0,fn23); stage B[q]k1(t+1)
    b1[0] = LDB(pBb, 0, 2);
    b1[1] = LDB(pBb, 0, 3);
    if (t + 1 < NT) stage_half(B, qBb + 16384, n0, (t + 1) * 64 + 32);
    asm volatile("s_barrier" ::: "memory");
    __builtin_amdgcn_s_setprio(1);
    #pragma unroll
    for (int f = 0; f < 8; ++f) {
      acc[f][0] = __builtin_amdgcn_mfma_f32_16x16x32_bf16(aA[f], b0[0], acc[f][0], 0, 0, 0);
      acc[f][1] = __builtin_amdgcn_mfma_f32_16x16x32_bf16(aA[f], b0[1], acc[f][1], 0, 0, 0);
    }
    __builtin_amdgcn_s_setprio(0);
    __builtin_amdgcn_sched_barrier(0);
    asm volatile("s_barrier" ::: "memory");

    // -------- phase 1: MFMA (k0, fn 2-3); read a(k1)+b(k1,fn01); stage A[p]k0(t+2)
    #pragma unroll
    for (int f = 0; f < 8; ++f) aB[f] = LDA(pAb, 1, f);
    b0[0] = LDB(pBb, 1, 0);
    b0[1] = LDB(pBb, 1, 1);
    if (t + 2 < NT) stage_half(A, pAb, m0, k2);
    asm volatile("s_barrier" ::: "memory");
    __builtin_amdgcn_s_setprio(1);
    #pragma unroll
    for (int f = 0; f < 8; ++f) {
      acc[f][2] = __builtin_amdgcn_mfma_f32_16x16x32_bf16(aA[f], b1[0], acc[f][2], 0, 0, 0);
      acc[f][3] = __builtin_amdgcn_mfma_f32_16x16x32_bf16(aA[f], b1[1], acc[f][3], 0, 0, 0);
    }
    __builtin_amdgcn_s_setprio(0);
    __builtin_amdgcn_sched_barrier(0);
    asm volatile("s_barrier" ::: "memory");

    // -------- phase 2: MFMA (k1, fn 0-1); read b(k1,fn23); stage B[p]k0(t+2)
    b1[0] = LDB(pBb, 1, 2);
    b1[1] = LDB(pBb, 1, 3);
    if (t + 2 < NT) stage_half(B, pBb, n0, k2);
    asm volatile("s_barrier" ::: "memory");
    __builtin_amdgcn_s_setprio(1);
    #pragma unroll
    for (int f = 0; f < 8; ++f) {
      acc[f][0] = __builtin_amdgcn_mfma_f32_16x16x32_bf16(aB[f], b0[0], acc[f][0], 0, 0, 0);
      acc[f][1] = __builtin_amdgcn_mfma_f32_16x16x32_bf16(aB[f], b0[1], acc[f][1], 0, 0, 0);
    }
    __builtin_amdgcn_s_setprio(0);
    __builtin_amdgcn_sched_barrier(0);
    asm volatile("s_barrier" ::: "memory");

    // -------- phase 3: MFMA (k1, fn 2-3); stage A[p]k1(t+2); vmcnt(6);
    //          then (after barrier) read next tile's a(k0)+b(k0,fn01)
    if (t + 2 < NT) stage_half(A, pAb + 16384, m0, k2 + 32);
    if (t < NT - 2)       asm volatile("s_waitcnt vmcnt(6)" ::: "memory");
    else if (t == NT - 2) asm volatile("s_waitcnt vmcnt(0)" ::: "memory");
    asm volatile("s_barrier" ::: "memory");
    if (t + 1 < NT) {
      #pragma unroll
      for (int f = 0; f < 8; ++f) aA[f] = LDA(qAb, 0, f);
      b0[0] = LDB(qBb, 0, 0);
      b0[1] = LDB(qBb, 0, 1);
    }
    __builtin_amdgcn_s_setprio(1);
    #pragma unroll
    for (int f = 0; f < 8; ++f) {
      acc[f][2] = __builtin_amdgcn_mfma_f32_16x16x32_bf16(aB[f], b1[0], acc[f][2], 0, 0, 0);
      acc[f][3] = __builtin_amdgcn_mfma_f32_16x16x32_bf16(aB[f], b1[1], acc[f][3], 0, 0, 0);
    }
    __builtin_amdgcn_s_setprio(0);
    __builtin_amdgcn_sched_barrier(0);
    asm volatile("s_barrier" ::: "memory");
  }

  // epilogue: C/D layout col = lane&15, row = quad*4 + j
  #pragma unroll
  for (int g = 0; g < 4; ++g) {
    const int col = n0 + wn + g * 16 + l16;
    const float bv = bias[col];
    #pragma unroll
    for (int f = 0; f < 8; ++f) {
      const int r0 = m0 + wm + f * 16 + quad * 4;
      #pragma unroll
      for (int j = 0; j < 4; ++j)
        out[(size_t)(r0 + j) * N + col] = acc[f][g][j] + bv;
    }
  }
}

// ---------------------------------------------------------------------------
extern "C" void kernel_launch(void* const* d_in, const int* in_sizes, int n_in,
                              void* d_out, int out_size, void* d_ws, size_t ws_size,
                              hipStream_t stream) {
  const float* x    = (const float*)d_in[0];   // [8,8192,1024] f32
  const float* wgt  = (const float*)d_in[1];   // [1024,1024] f32
  const float* bias = (const float*)d_in[2];   // [1024] f32
  float* out = (float*)d_out;                  // [8,8192,1024] f32

  const int K = 1024, N = 1024;
  const int M = in_sizes[0] / K;               // 65536

  u16* xq = (u16*)d_ws;                        // 128 MiB bf16
  u16* wq = xq + (size_t)M * K;                // 2 MiB bf16

  const int ngroups = (M * K) / 128;
  quant_kernel<<<ngroups / 16, 256, 0, stream>>>(x, xq);
  wconv_kernel<<<(N * K) / 1024, 256, 0, stream>>>(wgt, wq);
  gemm_kernel<<<(M / BM) * (N / BN), 512, 0, stream>>>(xq, wq, bias, out, M, N, K);
}

// Round 4
// 269.156 us; speedup vs baseline: 1.2081x; 1.0117x over previous
//
#include <hip/hip_runtime.h>

typedef unsigned int u32;
typedef unsigned short u16;

typedef __attribute__((ext_vector_type(8))) short short8v;   // 8 x bf16 bits
typedef __attribute__((ext_vector_type(4))) float f32x4;

#define AS_GLOBAL __attribute__((address_space(1)))
#define AS_LDS    __attribute__((address_space(3)))

static __device__ __forceinline__ u16 f32_bf16_rne(float f) {
  u32 u = __builtin_bit_cast(u32, f);
  u32 lsb = (u >> 16) & 1u;
  u += 0x7fffu + lsb;
  return (u16)(u >> 16);
}

// ---------------------------------------------------------------------------
// Pass 1: quotient-remainder fake quant, f32 -> bf16 bits.
// One group (GS=128) per 16-lane subgroup; 8 elems/lane.
// base >= 2 always, so reference's sel_mask (base < 1.0) is always false.
// ---------------------------------------------------------------------------
__global__ __launch_bounds__(256) void quant_kernel(
    const float* __restrict__ x, u16* __restrict__ xq) {
  const int tid = blockIdx.x * 256 + threadIdx.x;
  const int grp = tid >> 4;
  const int l   = tid & 15;
  const size_t base_e = (size_t)grp * 128;
  const float* gx = x + base_e;

  float4 v0 = *(const float4*)(gx + l * 4);
  float4 v1 = *(const float4*)(gx + 64 + l * 4);
  float xs[8] = {v0.x, v0.y, v0.z, v0.w, v1.x, v1.y, v1.z, v1.w};

  float mabs = 0.f;
  #pragma unroll
  for (int i = 0; i < 8; ++i) mabs = fmaxf(mabs, fabsf(xs[i]));
  #pragma unroll
  for (int s = 1; s < 16; s <<= 1) mabs = fmaxf(mabs, __shfl_xor(mabs, s, 16));
  mabs = fmaxf(mabs, 1e-8f);

  const float thr = mabs / 7.0f;            // true division: matches np
  float base = 64.f;
  base = (thr <= 32.f) ? 32.f : base;
  base = (thr <= 16.f) ? 16.f : base;
  base = (thr <= 8.f)  ? 8.f  : base;
  base = (thr <= 4.f)  ? 4.f  : base;
  base = (thr <= 2.f)  ? 2.f  : base;
  const float rbase = 1.0f / base;          // exact (power of 2)

  float q[8], r[8];
  float mr = 0.f;
  #pragma unroll
  for (int i = 0; i < 8; ++i) {
    float qq = rintf(xs[i] * rbase);        // == rintf(xs/base), exact scale
    qq = fminf(fmaxf(qq, -7.f), 7.f);
    q[i] = qq;
    r[i] = xs[i] - base * qq;               // exact product, IEEE sub
    mr = fmaxf(mr, fabsf(r[i]));
  }
  #pragma unroll
  for (int s = 1; s < 16; s <<= 1) mr = fmaxf(mr, __shfl_xor(mr, s, 16));
  float rs = fmaxf(mr, 1e-8f) / 7.0f;
  rs = fmaxf(rs, 1e-8f);

  u16 o[8];
  #pragma unroll
  for (int i = 0; i < 8; ++i) {
    float rd = rintf(r[i] / rs);            // IEEE division: matches np
    rd = fminf(fmaxf(rd, -8.f), 7.f) * rs;
    o[i] = f32_bf16_rne(q[i] * base + rd);
  }
  uint2 p0, p1;
  p0.x = (u32)o[0] | ((u32)o[1] << 16);
  p0.y = (u32)o[2] | ((u32)o[3] << 16);
  p1.x = (u32)o[4] | ((u32)o[5] << 16);
  p1.y = (u32)o[6] | ((u32)o[7] << 16);
  *(uint2*)(xq + base_e + l * 4) = p0;
  *(uint2*)(xq + base_e + 64 + l * 4) = p1;
}

// ---------------------------------------------------------------------------
// Pass 2: weight f32 -> bf16 bits.
// ---------------------------------------------------------------------------
__global__ __launch_bounds__(256) void wconv_kernel(
    const float* __restrict__ w, u16* __restrict__ wq) {
  const int i = (blockIdx.x * 256 + threadIdx.x) * 4;
  float4 v = *(const float4*)(w + i);
  uint2 p;
  p.x = (u32)f32_bf16_rne(v.x) | ((u32)f32_bf16_rne(v.y) << 16);
  p.y = (u32)f32_bf16_rne(v.z) | ((u32)f32_bf16_rne(v.w) << 16);
  *(uint2*)(wq + i) = p;
}

// ---------------------------------------------------------------------------
// Pass 3: bf16 MFMA GEMM, PERSISTENT: grid=256 (1 block/CU), each block does
// 4 output tiles (fixed nt, 4 mts within its XCD's mt range) as ONE
// continuous 64-step K-stream. 256x256 tile, BK=64, 8 waves (2Mx4N),
// 4 phases/K-step, K-half staging, counted vmcnt(6) that flows across tile
// boundaries (prologue paid once; epilogues overlap next tile's prefetch).
//
// LDS map (128 KiB): A[p] at p*32768, B[p] at 65536+p*32768; within buffer:
// ksub*16384 + row*64 + (kslot ^ ((row>>1)&3))*16. DMA dest linear; source
// pre-swizzled; ds_read applies same XOR -> bank-balanced b128 (conflict=0).
//
// Stage stream (3 half-tiles ahead, vmcnt(6) at ph3):
//   ph0: B[t+1] k1   ph1: A[t+2] k0   ph2: B[t+2] k0   ph3: A[t+2] k1
// At ph3(t) the 6 newest VMEM instrs are t+2 halves -> vmcnt(6) drains
// exactly through B-k1(t+1). Uniform across segment boundaries (16 even ->
// parity continuous). Epilogue stores drain under the next segment's ph3.
// ---------------------------------------------------------------------------
#define BM 256
#define BN 256
#define BK 64

__global__ __launch_bounds__(512, 2) void gemm_kernel(
    const u16* __restrict__ A, const u16* __restrict__ B,
    const float* __restrict__ bias, float* __restrict__ out,
    int M, int N, int K) {
  __shared__ u16 lds[65536];   // 128 KiB

  const int tid  = threadIdx.x;
  const int w    = tid >> 6;
  const int lane = tid & 63;
  const int l16  = lane & 15;
  const int quad = lane >> 4;

  // persistent-block tile assignment: 32 blocks/XCD, nt fixed per block,
  // mt = xcd*32 + (idx>>2) + 8*seg  (seg = t>>4) -> A panels stay XCD-local
  const int xcd = blockIdx.x & 7;
  const int idx = blockIdx.x >> 3;            // 0..31
  const int n0  = (idx & 3) * BN;
  const int mtl = idx >> 2;                   // 0..7
  const int mtb = xcd * 32 + mtl;
  const int wm = (w >> 2) * 128, wn = (w & 3) * 64;

  const int swz  = (quad ^ ((l16 >> 1) & 3)) << 4;
  const int aoff = (wm + l16) * 64 + swz;
  const int boff = (wn + l16) * 64 + swz;

  // m0 for logical K-step u
  auto m0_of = [&](int u) { return (mtb + 8 * (u >> 4)) * BM; };

  // stage one K-half (16 KB): 2 x global_load_lds dwordx4 per thread
  auto stage_half = [&](const u16* __restrict__ G, int base_b, int r0, int k0) {
    #pragma unroll
    for (int i = 0; i < 2; ++i) {
      const int c = w * 2 + i;                       // 0..15 chunks of 1 KiB
      const int row = c * 16 + (lane >> 2);
      const int kslot = (lane & 3) ^ ((lane >> 3) & 3);   // pre-swizzled src
      const u16* g = G + (size_t)(r0 + row) * K + (k0 + kslot * 8);
      __builtin_amdgcn_global_load_lds((const AS_GLOBAL u32*)(const void*)g,
          (AS_LDS u32*)(void*)((char*)lds + base_b + c * 1024), 16, 0, 0);
    }
  };

  auto LDA = [&](int base_b, int s, int f) {
    return *(const short8v*)((const char*)lds + base_b + s * 16384 + f * 1024 + aoff);
  };
  auto LDB = [&](int base_b, int s, int g) {
    return *(const short8v*)((const char*)lds + base_b + s * 16384 + g * 1024 + boff);
  };

  f32x4 acc[8][4];
  #pragma unroll
  for (int f = 0; f < 8; ++f)
    #pragma unroll
    for (int g = 0; g < 4; ++g)
      acc[f][g] = (f32x4){0.f, 0.f, 0.f, 0.f};

  short8v aA[8], aB[8], b0[2], b1[2];

  const int NTOT = (K / BK) * 4;   // 64 continuous K-steps (4 segments of 16)

  // prologue (once per block): tile0's 4 halves + tile1's first 3, in order
  stage_half(A, 0,             m0_of(0), 0);
  stage_half(B, 65536,         n0, 0);
  stage_half(A, 16384,         m0_of(0), 32);
  stage_half(B, 65536 + 16384, n0, 32);
  stage_half(A, 32768,         m0_of(1), 64);
  stage_half(B, 65536 + 32768, n0, 64);
  stage_half(A, 32768 + 16384, m0_of(1), 96);
  asm volatile("s_waitcnt vmcnt(6)" ::: "memory");   // step0's 8 loads done
  asm volatile("s_barrier" ::: "memory");

  // pre-issue reads for t=0 phase 0 (parity 0)
  #pragma unroll
  for (int f = 0; f < 8; ++f) aA[f] = LDA(0, 0, f);
  b0[0] = LDB(65536, 0, 0);
  b0[1] = LDB(65536, 0, 1);

  for (int t = 0; t < NTOT; ++t) {
    const int p   = t & 1;
    const int pAb = p * 32768;
    const int pBb = 65536 + p * 32768;
    const int qAb = (p ^ 1) * 32768;
    const int qBb = 65536 + (p ^ 1) * 32768;
    const int k1s = ((t + 1) & 15) * 64;    // k0 of step t+1
    const int k2s = ((t + 2) & 15) * 64;    // k0 of step t+2

    // -------- phase 0: MFMA (k0, fn 0-1); read b(k0,fn23); stage B[t+1]k1
    b1[0] = LDB(pBb, 0, 2);
    b1[1] = LDB(pBb, 0, 3);
    if (t + 1 < NTOT) stage_half(B, qBb + 16384, n0, k1s + 32);
    asm volatile("s_barrier" ::: "memory");
    __builtin_amdgcn_s_setprio(1);
    #pragma unroll
    for (int f = 0; f < 8; ++f) {
      acc[f][0] = __builtin_amdgcn_mfma_f32_16x16x32_bf16(aA[f], b0[0], acc[f][0], 0, 0, 0);
      acc[f][1] = __builtin_amdgcn_mfma_f32_16x16x32_bf16(aA[f], b0[1], acc[f][1], 0, 0, 0);
    }
    __builtin_amdgcn_s_setprio(0);
    __builtin_amdgcn_sched_barrier(0);
    asm volatile("s_barrier" ::: "memory");

    // -------- phase 1: MFMA (k0, fn 2-3); read a(k1)+b(k1,fn01); stage A[t+2]k0
    #pragma unroll
    for (int f = 0; f < 8; ++f) aB[f] = LDA(pAb, 1, f);
    b0[0] = LDB(pBb, 1, 0);
    b0[1] = LDB(pBb, 1, 1);
    if (t + 2 < NTOT) stage_half(A, pAb, m0_of(t + 2), k2s);
    asm volatile("s_barrier" ::: "memory");
    __builtin_amdgcn_s_setprio(1);
    #pragma unroll
    for (int f = 0; f < 8; ++f) {
      acc[f][2] = __builtin_amdgcn_mfma_f32_16x16x32_bf16(aA[f], b1[0], acc[f][2], 0, 0, 0);
      acc[f][3] = __builtin_amdgcn_mfma_f32_16x16x32_bf16(aA[f], b1[1], acc[f][3], 0, 0, 0);
    }
    __builtin_amdgcn_s_setprio(0);
    __builtin_amdgcn_sched_barrier(0);
    asm volatile("s_barrier" ::: "memory");

    // -------- phase 2: MFMA (k1, fn 0-1); read b(k1,fn23); stage B[t+2]k0
    b1[0] = LDB(pBb, 1, 2);
    b1[1] = LDB(pBb, 1, 3);
    if (t + 2 < NTOT) stage_half(B, pBb, n0, k2s);
    asm volatile("s_barrier" ::: "memory");
    __builtin_amdgcn_s_setprio(1);
    #pragma unroll
    for (int f = 0; f < 8; ++f) {
      acc[f][0] = __builtin_amdgcn_mfma_f32_16x16x32_bf16(aB[f], b0[0], acc[f][0], 0, 0, 0);
      acc[f][1] = __builtin_amdgcn_mfma_f32_16x16x32_bf16(aB[f], b0[1], acc[f][1], 0, 0, 0);
    }
    __builtin_amdgcn_s_setprio(0);
    __builtin_amdgcn_sched_barrier(0);
    asm volatile("s_barrier" ::: "memory");

    // -------- phase 3: MFMA (k1, fn 2-3); stage A[t+2]k1; vmcnt(6);
    //          then (after barrier) read step t+1's a(k0)+b(k0,fn01)
    if (t + 2 < NTOT) stage_half(A, pAb + 16384, m0_of(t + 2), k2s + 32);
    if (t < NTOT - 2)       asm volatile("s_waitcnt vmcnt(6)" ::: "memory");
    else if (t == NTOT - 2) asm volatile("s_waitcnt vmcnt(0)" ::: "memory");
    asm volatile("s_barrier" ::: "memory");
    if (t + 1 < NTOT) {
      #pragma unroll
      for (int f = 0; f < 8; ++f) aA[f] = LDA(qAb, 0, f);
      b0[0] = LDB(qBb, 0, 0);
      b0[1] = LDB(qBb, 0, 1);
    }
    __builtin_amdgcn_s_setprio(1);
    #pragma unroll
    for (int f = 0; f < 8; ++f) {
      acc[f][2] = __builtin_amdgcn_mfma_f32_16x16x32_bf16(aB[f], b1[0], acc[f][2], 0, 0, 0);
      acc[f][3] = __builtin_amdgcn_mfma_f32_16x16x32_bf16(aB[f], b1[1], acc[f][3], 0, 0, 0);
    }
    __builtin_amdgcn_s_setprio(0);
    __builtin_amdgcn_sched_barrier(0);
    asm volatile("s_barrier" ::: "memory");

    // -------- segment epilogue: flush acc, zero, keep streaming
    if ((t & 15) == 15) {
      const int m0 = m0_of(t);
      #pragma unroll
      for (int g = 0; g < 4; ++g) {
        const int col = n0 + wn + g * 16 + l16;
        const float bv = bias[col];
        #pragma unroll
        for (int f = 0; f < 8; ++f) {
          const int r0 = m0 + wm + f * 16 + quad * 4;
          #pragma unroll
          for (int j = 0; j < 4; ++j)
            out[(size_t)(r0 + j) * N + col] = acc[f][g][j] + bv;
        }
      }
      #pragma unroll
      for (int f = 0; f < 8; ++f)
        #pragma unroll
        for (int g = 0; g < 4; ++g)
          acc[f][g] = (f32x4){0.f, 0.f, 0.f, 0.f};
    }
  }
}

// ---------------------------------------------------------------------------
extern "C" void kernel_launch(void* const* d_in, const int* in_sizes, int n_in,
                              void* d_out, int out_size, void* d_ws, size_t ws_size,
                              hipStream_t stream) {
  const float* x    = (const float*)d_in[0];   // [8,8192,1024] f32
  const float* wgt  = (const float*)d_in[1];   // [1024,1024] f32
  const float* bias = (const float*)d_in[2];   // [1024] f32
  float* out = (float*)d_out;                  // [8,8192,1024] f32

  const int K = 1024, N = 1024;
  const int M = in_sizes[0] / K;               // 65536

  u16* xq = (u16*)d_ws;                        // 128 MiB bf16
  u16* wq = xq + (size_t)M * K;                // 2 MiB bf16

  const int ngroups = (M * K) / 128;
  quant_kernel<<<ngroups / 16, 256, 0, stream>>>(x, xq);
  wconv_kernel<<<(N * K) / 1024, 256, 0, stream>>>(wgt, wq);
  gemm_kernel<<<256, 512, 0, stream>>>(xq, wq, bias, out, M, N, K);
}